// Round 8
// baseline (254.179 us; speedup 1.0000x reference)
//
#include <hip/hip_runtime.h>
#include <math.h>

typedef float v2f __attribute__((ext_vector_type(2)));

// Head-weight table transposed [c][hw] (float4 = {bw0,bw1,bw2,patc}) so a
// channel-slab load is lane-coalesced (lane = pixel hw).
__device__ float4 g_wqt[131072];
// Conv weights pair-major: per channel-pair p: 27 tap-pairs, bias pair,
// match_w pair. Read with wave-uniform indices -> scalarized to s_load.
__device__ v2f g_cwt[64 * 29];
// Partial head sums: [256 samples][16 channel-groups][5].
__device__ float g_part[256 * 16 * 5];

// ---------------------------------------------------------------------------
// Prep: build g_wqt (fused base+pat head, transposed) and g_cwt.
// ---------------------------------------------------------------------------
__global__ __launch_bounds__(256)
void prep_weights(const float* __restrict__ base_w,  // [131072,3]
                  const float* __restrict__ pat_w,   // [32768]
                  const int*   __restrict__ psi,     // [32]
                  const float* __restrict__ conv_w,  // [27,128]
                  const float* __restrict__ conv_b,  // [128]
                  const float* __restrict__ match_w) // [128]
{
    int idx = blockIdx.x * 256 + threadIdx.x;        // 0..131071
    int c = idx >> 10, hw = idx & 1023;
    const float* bp = base_w + ((size_t)hw * 128 + c) * 3;
    float pc = 0.f;
    const float* pr = pat_w + hw * 32;
    #pragma unroll
    for (int k = 0; k < 32; ++k)
        pc += (psi[k] == c) ? pr[k] : 0.f;
    g_wqt[idx] = make_float4(bp[0], bp[1], bp[2], pc);

    if (idx < 64 * 29) {
        int p = idx / 29, r = idx - p * 29;
        v2f v;
        if (r < 27)       v = (v2f){ conv_w[r * 128 + 2 * p], conv_w[r * 128 + 2 * p + 1] };
        else if (r == 27) v = (v2f){ conv_b[2 * p], conv_b[2 * p + 1] };
        else              v = (v2f){ match_w[2 * p], match_w[2 * p + 1] };
        g_cwt[idx] = v;
    }
}

// ---------------------------------------------------------------------------
// Main kernel: block = (sample-group of 16) x (channel-group of 8 channels).
// blk = cg*16 + sg  =>  XCD (blk%8) = sg%8: all 16 cg-blocks of a sample
// group share one XCD's L2 for the input images.
// The 8-channel table slice (8 float4/thread, lane = pixel) is loaded ONCE
// into registers and reused across 16 samples -- kills the per-sample 2 MB
// table stream that every previous variant paid (512 MB -> 32 MB L2 reads).
// Thread = output pixel; per sample: prefetch next image, stencil from LDS,
// 4 packed-fp32 channel-pair convs (weights via s_load), wave-level reduce
// into an LDS slot (no per-sample block barrier for the reduction).
// ---------------------------------------------------------------------------
__global__ __launch_bounds__(1024, 4)
void pattern_branch_kernel(const float* __restrict__ in)      // [B,64,64,3]
{
    __shared__ float xf[65 * 200];       // padded image, 52 KB
    __shared__ float red[16][16][5];     // [sample][wave][5], 5 KB

    const int blk = blockIdx.x;
    const int sg  = blk & 15;            // sample group (fast -> XCD-local)
    const int cg  = blk >> 4;            // channel group: channels 8cg..8cg+7
    const int b0  = sg * 16;
    const int tid = threadIdx.x;

    // ---- table slice into registers: 4 pairs x 2 channels, lane = hw = tid
    float4 tA[4], tB[4];
    #pragma unroll
    for (int pp = 0; pp < 4; ++pp) {
        int p = cg * 4 + pp;
        tA[pp] = g_wqt[(2 * p) * 1024 + tid];
        tB[pp] = g_wqt[(2 * p + 1) * 1024 + tid];
    }

    // ---- zero LDS once (pad row 64 / col tail stay 0 across samples)
    float4* x4 = (float4*)xf;
    for (int s = tid; s < 65 * 50; s += 1024) x4[s] = make_float4(0.f, 0.f, 0.f, 0.f);
    __syncthreads();

    // ---- stage sample 0
    {
        const float4* ip = (const float4*)(in + (size_t)b0 * 12288);
        #pragma unroll
        for (int j = 0; j < 3; ++j) {
            int s = tid + j * 1024;      // 0..3071 = 64 rows x 48 float4
            int r = s / 48, q = s - r * 48;
            x4[r * 50 + q] = ip[s];
        }
    }
    __syncthreads();

    const int oh = tid >> 5;
    const int ow = tid & 31;

    for (int smp = 0; smp < 16; ++smp) {
        // ---- prefetch next sample's image into registers (hides HBM/L2)
        float4 pf[3];
        if (smp < 15) {
            const float4* ip = (const float4*)(in + (size_t)(b0 + smp + 1) * 12288);
            #pragma unroll
            for (int j = 0; j < 3; ++j) pf[j] = ip[tid + j * 1024];
        }

        // ---- per-thread stencil: rows 2oh..2oh+2, floats 6ow..6ow+8
        v2f xs[15];
        #pragma unroll
        for (int kh = 0; kh < 3; ++kh) {
            int rowoff = (2 * oh + kh) * 200 + 6 * ow;   // even -> 8B aligned
            #pragma unroll
            for (int u = 0; u < 5; ++u)
                xs[kh * 5 + u] = *(const v2f*)&xf[rowoff + 2 * u];
        }

        v2f sm2  = (v2f){0.f, 0.f};
        v2f sb01 = (v2f){0.f, 0.f};
        v2f sb2p = (v2f){0.f, 0.f};

        #pragma unroll
        for (int pp = 0; pp < 4; ++pp) {
            const v2f* wp = g_cwt + (cg * 4 + pp) * 29;  // uniform -> s_load
            v2f accA = wp[27];                           // bias pair
            v2f accB = (v2f){0.f, 0.f};
            #pragma unroll
            for (int kh = 0; kh < 3; ++kh)
                #pragma unroll
                for (int t9 = 0; t9 < 9; ++t9) {
                    float xv = xs[kh * 5 + (t9 >> 1)][t9 & 1];
                    v2f wv = wp[kh * 9 + t9];
                    if (t9 & 1) accB = __builtin_elementwise_fma((v2f){xv, xv}, wv, accB);
                    else        accA = __builtin_elementwise_fma((v2f){xv, xv}, wv, accA);
                }
            v2f f2 = __builtin_elementwise_max(accA + accB, (v2f){0.f, 0.f});

            float4 wv0 = tA[pp];                         // table in registers
            float4 wv1 = tB[pp];
            sm2  = __builtin_elementwise_fma(wp[28], f2, sm2);
            sb01 = __builtin_elementwise_fma((v2f){f2.x, f2.x}, (v2f){wv0.x, wv0.y}, sb01);
            sb01 = __builtin_elementwise_fma((v2f){f2.y, f2.y}, (v2f){wv1.x, wv1.y}, sb01);
            sb2p = __builtin_elementwise_fma((v2f){f2.x, f2.x}, (v2f){wv0.z, wv0.w}, sb2p);
            sb2p = __builtin_elementwise_fma((v2f){f2.y, f2.y}, (v2f){wv1.z, wv1.w}, sb2p);
        }

        // ---- wave-level reduce, write slot (no block barrier here)
        float vals[5] = { sm2.x + sm2.y, sb01.x, sb01.y, sb2p.x, sb2p.y };
        #pragma unroll
        for (int off = 32; off > 0; off >>= 1)
            #pragma unroll
            for (int v = 0; v < 5; ++v)
                vals[v] += __shfl_down(vals[v], off, 64);
        if ((tid & 63) == 0) {
            #pragma unroll
            for (int v = 0; v < 5; ++v) red[smp][tid >> 6][v] = vals[v];
        }

        // ---- rotate staged image
        if (smp < 15) {
            __syncthreads();             // all stencil reads of smp done
            #pragma unroll
            for (int j = 0; j < 3; ++j) {
                int s = tid + j * 1024;
                int r = s / 48, q = s - r * 48;
                x4[r * 50 + q] = pf[j];
            }
            __syncthreads();             // writes visible before next reads
        }
    }

    // ---- final cross-wave reduction for all 16 samples in parallel
    __syncthreads();
    if (tid < 16 * 5) {
        int s = tid / 5, v = tid - s * 5;
        float t = 0.f;
        #pragma unroll
        for (int w = 0; w < 16; ++w) t += red[s][w][v];
        g_part[((b0 + s) * 16 + cg) * 5 + v] = t;
    }
}

// ---------------------------------------------------------------------------
// Finish kernel: sum the 16 channel-group partials per sample, apply heads.
// ---------------------------------------------------------------------------
__global__ __launch_bounds__(256)
void finish_kernel(const float* __restrict__ match_b,
                   const float* __restrict__ pat_b,
                   const float* __restrict__ base_b,
                   float* __restrict__ out, int B)
{
    int b = blockIdx.x * 256 + threadIdx.x;
    if (b >= B) return;
    float t[5] = {0.f, 0.f, 0.f, 0.f, 0.f};
    for (int cg = 0; cg < 16; ++cg)
        #pragma unroll
        for (int v = 0; v < 5; ++v)
            t[v] += g_part[(b * 16 + cg) * 5 + v];
    float score = t[0] * (1.f / 1024.f) + match_b[0];
    float p = 1.f / (1.f + expf(-(t[4] + pat_b[0])));
    float l0 = t[1] + base_b[0], l1 = t[2] + base_b[1], l2 = t[3] + base_b[2];
    float m = fmaxf(l0, fmaxf(l1, l2));
    float e0 = expf(l0 - m), e1 = expf(l1 - m), e2 = expf(l2 - m);
    float inv = 1.f / (e0 + e1 + e2);
    bool use_pat = (score > 0.f) && (p >= 0.5f);
    float o0, o1, o2;
    if (use_pat) { o0 = p; o1 = 0.5f * (1.f - p); o2 = o1; }
    else         { o0 = e0 * inv; o1 = e1 * inv; o2 = e2 * inv; }
    out[b * 3 + 0] = o0;
    out[b * 3 + 1] = o1;
    out[b * 3 + 2] = o2;
}

extern "C" void kernel_launch(void* const* d_in, const int* in_sizes, int n_in,
                              void* d_out, int out_size, void* d_ws, size_t ws_size,
                              hipStream_t stream) {
    const float* in      = (const float*)d_in[0];
    const float* conv_w  = (const float*)d_in[1];
    const float* conv_b  = (const float*)d_in[2];
    const float* match_w = (const float*)d_in[3];
    const float* match_b = (const float*)d_in[4];
    const float* pat_w   = (const float*)d_in[5];
    const float* pat_b   = (const float*)d_in[6];
    const float* base_w  = (const float*)d_in[7];
    const float* base_b  = (const float*)d_in[8];
    const int*   psi     = (const int*)d_in[9];
    float* out = (float*)d_out;

    (void)d_ws; (void)ws_size;  // workspace unused

    prep_weights<<<512, 256, 0, stream>>>(base_w, pat_w, psi, conv_w, conv_b, match_w);

    pattern_branch_kernel<<<256, 1024, 0, stream>>>(in);

    int B = in_sizes[0] / (64 * 64 * 3);   // 256
    finish_kernel<<<(B + 255) / 256, 256, 0, stream>>>(match_b, pat_b, base_b, out, B);
}

// Round 9
// 215.132 us; speedup vs baseline: 1.1815x; 1.1815x over previous
//
#include <hip/hip_runtime.h>
#include <math.h>

typedef float v2f __attribute__((ext_vector_type(2)));

// Head-weight table transposed [c][hw] (float4 = {bw0,bw1,bw2,patc}).
__device__ float4 g_wqt[131072];
// Conv weights pair-major: per channel-pair p: 27 tap-pairs, bias pair,
// match_w pair. Read wave-uniformly -> scalarized to s_load.
__device__ v2f g_cwt[64 * 29];
// Partial head sums: [256 samples][32 rowblocks][5].
__device__ float g_part[256 * 32 * 5];

// ---------------------------------------------------------------------------
// Prep: build g_wqt (fused base+pat head, transposed) and g_cwt.
// ---------------------------------------------------------------------------
__global__ __launch_bounds__(256)
void prep_weights(const float* __restrict__ base_w,  // [131072,3]
                  const float* __restrict__ pat_w,   // [32768]
                  const int*   __restrict__ psi,     // [32]
                  const float* __restrict__ conv_w,  // [27,128]
                  const float* __restrict__ conv_b,  // [128]
                  const float* __restrict__ match_w) // [128]
{
    int idx = blockIdx.x * 256 + threadIdx.x;        // 0..131071
    int c = idx >> 10, hw = idx & 1023;
    const float* bp = base_w + ((size_t)hw * 128 + c) * 3;
    float pc = 0.f;
    const float* pr = pat_w + hw * 32;
    #pragma unroll
    for (int k = 0; k < 32; ++k)
        pc += (psi[k] == c) ? pr[k] : 0.f;
    g_wqt[idx] = make_float4(bp[0], bp[1], bp[2], pc);

    if (idx < 64 * 29) {
        int p = idx / 29, r = idx - p * 29;
        v2f v;
        if (r < 27)       v = (v2f){ conv_w[r * 128 + 2 * p], conv_w[r * 128 + 2 * p + 1] };
        else if (r == 27) v = (v2f){ conv_b[2 * p], conv_b[2 * p + 1] };
        else              v = (v2f){ match_w[2 * p], match_w[2 * p + 1] };
        g_cwt[idx] = v;
    }
}

// ---------------------------------------------------------------------------
// Main kernel: block = (output row rb 0..31) x (sample group of 16).
// blk = g + 16*rb  =>  XCD (blk%8) = g%8: a group's 16 images are XCD-local.
// The 64 KB table slice tbl[128ch][32px] lives in LDS for the whole block
// (r8's register-cache spilled; LDS is the right home). 8 sample-pair
// iterations: lane-half h in {0,1} processes sample 2it+h (stencil reads
// bank-uniform, table reads half-wave broadcast). Channel-pair loop is
// 4 pairs per wave, wave-uniform index -> conv weights via s_load.
// Per-sample 5-value shuffle reduce -> red -> g_part[sample][rb][5].
// ---------------------------------------------------------------------------
__global__ __launch_bounds__(1024, 4)
void pattern_branch_kernel(const float* __restrict__ in)      // [B,64,64,3]
{
    __shared__ float4 tbl[128 * 32];      // 64 KB: [c][px]
    __shared__ float  xb[4 * 636];        // 10.2 KB: [pairparity*2+sampparity][3*212]
    __shared__ float  red[16][16][5];     // 5 KB: [sample][wave][5]

    const int blk = blockIdx.x;
    const int g   = blk & 15;             // sample group -> XCD = g%8
    const int rb  = blk >> 4;             // output row 0..31
    const int b0  = g * 16;
    const int tid = threadIdx.x;

    // ---- table slice: 4096 float4, coalesced (32 consecutive f4 per c)
    #pragma unroll
    for (int j = 0; j < 4; ++j) {
        int idx = j * 1024 + tid;
        tbl[idx] = g_wqt[(idx >> 5) * 1024 + rb * 32 + (idx & 31)];
    }
    // ---- zero x buffers (col pad 192..211 and possible row-64 stay zero)
    for (int s = tid; s < 4 * 636; s += 1024) xb[s] = 0.f;
    __syncthreads();

    // ---- prologue: stage samples 0,1 into pair-parity-0 buffers
    if (tid < 288) {
        int sp = tid / 144, s2 = tid - sp * 144;
        int r3 = s2 / 48, q = s2 - r3 * 48;
        int gr = 2 * rb + r3;
        if (gr < 64)
            *(float4*)&xb[sp * 636 + r3 * 212 + q * 4] =
                ((const float4*)(in + (size_t)(b0 + sp) * 12288))[gr * 48 + q];
    }
    __syncthreads();

    const int px   = tid & 31;
    const int h    = (tid >> 5) & 1;      // sample-parity this lane handles
    const int wvid = tid >> 6;            // wave 0..15
    const int lane = tid & 63;

    for (int it = 0; it < 8; ++it) {
        // ---- stage next sample pair into the other buffers (no conflict)
        if (it < 7 && tid < 288) {
            int sp = tid / 144, s2 = tid - sp * 144;
            int r3 = s2 / 48, q = s2 - r3 * 48;
            int gr = 2 * rb + r3;
            if (gr < 64)
                *(float4*)&xb[(((it + 1) & 1) * 2 + sp) * 636 + r3 * 212 + q * 4] =
                    ((const float4*)(in + (size_t)(b0 + 2 * it + 2 + sp) * 12288))[gr * 48 + q];
        }

        // ---- stencil for (sample 2it+h, pixel px): rows kh, floats 6px..6px+9
        const float* xbase = &xb[((it & 1) * 2 + h) * 636];
        v2f xs[15];
        #pragma unroll
        for (int kh = 0; kh < 3; ++kh)
            #pragma unroll
            for (int u = 0; u < 5; ++u)
                xs[kh * 5 + u] = *(const v2f*)&xbase[kh * 212 + 6 * px + 2 * u];

        v2f sm2  = (v2f){0.f, 0.f};
        v2f sb01 = (v2f){0.f, 0.f};
        v2f sb2p = (v2f){0.f, 0.f};

        #pragma unroll
        for (int j = 0; j < 4; ++j) {
            int p = wvid * 4 + j;                    // wave-uniform -> s_load
            const v2f* wp = g_cwt + p * 29;
            v2f accA = wp[27];                       // bias pair
            v2f accB = (v2f){0.f, 0.f};
            #pragma unroll
            for (int kh = 0; kh < 3; ++kh)
                #pragma unroll
                for (int t9 = 0; t9 < 9; ++t9) {
                    float xv = xs[kh * 5 + (t9 >> 1)][t9 & 1];
                    v2f wv = wp[kh * 9 + t9];
                    if (t9 & 1) accB = __builtin_elementwise_fma((v2f){xv, xv}, wv, accB);
                    else        accA = __builtin_elementwise_fma((v2f){xv, xv}, wv, accA);
                }
            v2f f2 = __builtin_elementwise_max(accA + accB, (v2f){0.f, 0.f});

            float4 wv0 = tbl[(2 * p) * 32 + px];     // contiguous 512B + bcast
            float4 wv1 = tbl[(2 * p + 1) * 32 + px];
            sm2  = __builtin_elementwise_fma(wp[28], f2, sm2);
            sb01 = __builtin_elementwise_fma((v2f){f2.x, f2.x}, (v2f){wv0.x, wv0.y}, sb01);
            sb01 = __builtin_elementwise_fma((v2f){f2.y, f2.y}, (v2f){wv1.x, wv1.y}, sb01);
            sb2p = __builtin_elementwise_fma((v2f){f2.x, f2.x}, (v2f){wv0.z, wv0.w}, sb2p);
            sb2p = __builtin_elementwise_fma((v2f){f2.y, f2.y}, (v2f){wv1.z, wv1.w}, sb2p);
        }

        // ---- per-sample reduce over the 32 px lanes of this half-wave
        float vals[5] = { sm2.x + sm2.y, sb01.x, sb01.y, sb2p.x, sb2p.y };
        #pragma unroll
        for (int m = 1; m <= 16; m <<= 1)
            #pragma unroll
            for (int v = 0; v < 5; ++v)
                vals[v] += __shfl_xor(vals[v], m, 64);
        if (lane == 0 || lane == 32) {
            #pragma unroll
            for (int v = 0; v < 5; ++v) red[2 * it + h][wvid][v] = vals[v];
        }

        __syncthreads();   // staging visible; reads done before overwrite
    }

    // ---- fold 16 waves per sample, write partials
    if (tid < 16 * 5) {
        int s = tid / 5, v = tid - s * 5;
        float t = 0.f;
        #pragma unroll
        for (int w = 0; w < 16; ++w) t += red[s][w][v];
        g_part[((b0 + s) * 32 + rb) * 5 + v] = t;
    }
}

// ---------------------------------------------------------------------------
// Finish kernel: sum the 32 rowblock partials per sample, apply heads.
// ---------------------------------------------------------------------------
__global__ __launch_bounds__(256)
void finish_kernel(const float* __restrict__ match_b,
                   const float* __restrict__ pat_b,
                   const float* __restrict__ base_b,
                   float* __restrict__ out, int B)
{
    int b = blockIdx.x * 256 + threadIdx.x;
    if (b >= B) return;
    float t[5] = {0.f, 0.f, 0.f, 0.f, 0.f};
    for (int rb = 0; rb < 32; ++rb)
        #pragma unroll
        for (int v = 0; v < 5; ++v)
            t[v] += g_part[(b * 32 + rb) * 5 + v];
    float score = t[0] * (1.f / 1024.f) + match_b[0];
    float p = 1.f / (1.f + expf(-(t[4] + pat_b[0])));
    float l0 = t[1] + base_b[0], l1 = t[2] + base_b[1], l2 = t[3] + base_b[2];
    float m = fmaxf(l0, fmaxf(l1, l2));
    float e0 = expf(l0 - m), e1 = expf(l1 - m), e2 = expf(l2 - m);
    float inv = 1.f / (e0 + e1 + e2);
    bool use_pat = (score > 0.f) && (p >= 0.5f);
    float o0, o1, o2;
    if (use_pat) { o0 = p; o1 = 0.5f * (1.f - p); o2 = o1; }
    else         { o0 = e0 * inv; o1 = e1 * inv; o2 = e2 * inv; }
    out[b * 3 + 0] = o0;
    out[b * 3 + 1] = o1;
    out[b * 3 + 2] = o2;
}

extern "C" void kernel_launch(void* const* d_in, const int* in_sizes, int n_in,
                              void* d_out, int out_size, void* d_ws, size_t ws_size,
                              hipStream_t stream) {
    const float* in      = (const float*)d_in[0];
    const float* conv_w  = (const float*)d_in[1];
    const float* conv_b  = (const float*)d_in[2];
    const float* match_w = (const float*)d_in[3];
    const float* match_b = (const float*)d_in[4];
    const float* pat_w   = (const float*)d_in[5];
    const float* pat_b   = (const float*)d_in[6];
    const float* base_w  = (const float*)d_in[7];
    const float* base_b  = (const float*)d_in[8];
    const int*   psi     = (const int*)d_in[9];
    float* out = (float*)d_out;

    (void)d_ws; (void)ws_size;  // workspace unused

    prep_weights<<<512, 256, 0, stream>>>(base_w, pat_w, psi, conv_w, conv_b, match_w);

    int B = in_sizes[0] / (64 * 64 * 3);   // 256
    pattern_branch_kernel<<<32 * (B / 16), 1024, 0, stream>>>(in);
    finish_kernel<<<(B + 255) / 256, 256, 0, stream>>>(match_b, pat_b, base_b, out, B);
}